// Round 8
// baseline (352.956 us; speedup 1.0000x reference)
//
#include <hip/hip_runtime.h>

// Problem constants
#define B 8
#define N 4096
#define C 128
#define C2 256          // K-dim of fused GEMM: [ptl | s]
#define KNN 21          // top-(K+1), drop nearest

typedef unsigned long long u64;
typedef unsigned int u32;
typedef unsigned short u16;

typedef __attribute__((ext_vector_type(8))) short bf16x8;
typedef __attribute__((ext_vector_type(4))) float f32x4;

__device__ __forceinline__ float bf2f(u16 u) {
    return __uint_as_float(((u32)u) << 16);
}
__device__ __forceinline__ u16 f2bf(float f) {  // round-to-nearest-even
    u32 x = __float_as_uint(f);
    return (u16)((x + 0x7FFFu + ((x >> 16) & 1u)) >> 16);
}

// ---------------------------------------------------------------------------
// K1: transpose + leaky_relu: points (B,C,N) f32 -> X[b][n][c] (c<128) bf16
// ---------------------------------------------------------------------------
__global__ __launch_bounds__(256) void k_transpose_lrelu(
        const float* __restrict__ pts, u16* __restrict__ X) {
    __shared__ u16 tile[32][33];
    int b  = blockIdx.z;
    int c0 = blockIdx.y * 32;
    int n0 = blockIdx.x * 32;
    int tx = threadIdx.x, ty = threadIdx.y;   // 32 x 8
    const float* src = pts + (size_t)b * C * N;
    #pragma unroll
    for (int i = 0; i < 32; i += 8) {
        float v = src[(size_t)(c0 + ty + i) * N + n0 + tx];
        if (v < 0.f) v = __fmul_rn(v, 0.01f);
        tile[ty + i][tx] = f2bf(v);
    }
    __syncthreads();
    u16* dst = X + (size_t)b * N * C2;
    #pragma unroll
    for (int i = 0; i < 32; i += 8) {
        dst[(size_t)(n0 + ty + i) * C2 + (c0 + tx)] = tile[tx][ty + i];
    }
}

// ---------------------------------------------------------------------------
// K2: exact KNN (top-21 by (sq, idx), drop min) + neighbor-feature gather-sum.
// Grid 1024 blocks. Block = 32 queries, 256 thr = 4 waves.
// Lane l -> (query l>>1, candidate-half l&1); lane scans 512 candidates.
// Selection: data-oblivious, in-place. List L[0..20] asc stays put; chunk of
// 8 Batcher-sorted desc into Cc[0..7] (19 CE); pruned bitonic merge-32 over
// (L asc | 3x +inf phantom | Cc desc) -> lowest 21 back in L (61 CE + 3 mov).
// Keys u64 (sortable_bits<<32 | idx): exact np top_k tie-break.
// __launch_bounds__(256,4): 128-VGPR budget, prevents the R7 scratch spill.
// ---------------------------------------------------------------------------
__global__ __launch_bounds__(256, 4) void k_knn_gather(
        const float* __restrict__ xyz, u16* __restrict__ X) {
    __shared__ __align__(16) char lds[32256];
    float4* stg = (float4*)lds;                       // [4][256] 16384 B (phase A)
    u32*    mk  = (u32*)lds;                          // [256][21] 21504 B (phase B)
    u16*    mi  = (u16*)(lds + 21504);                // [256][21] 10752 B (phase B)
    __shared__ u16 win[32 * KNN];

    int tid = threadIdx.x;
    int w = tid >> 6, l = tid & 63;
    int q = l >> 1, h = l & 1;
    int b = blockIdx.y;
    int n0 = blockIdx.x * 32;
    int nq = n0 + q;

    const float* xz = xyz + (size_t)b * 3 * N;
    // query point (np formula: ((x*x + y*y) + z*z))
    float qx = xz[nq], qy = xz[N + nq], qz = xz[2 * N + nq];
    float snq = __fadd_rn(__fadd_rn(__fmul_rn(qx, qx), __fmul_rn(qy, qy)),
                          __fmul_rn(qz, qz));

    u64 L[KNN];                                       // positions 0..20 (asc)
    u64 E[3];                                         // positions 21..23
    u64 Cc[8];                                        // positions 24..31 (desc)
    #pragma unroll
    for (int i = 0; i < KNN; ++i) L[i] = ~0ull;

    // lvalue position map for the merge network
    #define V(p) ((p) <= 20 ? L[p] : ((p) <= 23 ? E[(p) - 21] : Cc[(p) - 24]))

    for (int sc = 0; sc < 4; ++sc) {
        // stage 2x128 candidates (x,y,z,sq_norm) for this wave's two halves
        #pragma unroll
        for (int r = 0; r < 4; ++r) {
            int e = l + 64 * r;                       // 0..255
            int he = e >> 7, je = e & 127;
            int m = w * 1024 + he * 512 + sc * 128 + je;
            float x = xz[m], y = xz[N + m], z = xz[2 * N + m];
            float sn = __fadd_rn(__fadd_rn(__fmul_rn(x, x), __fmul_rn(y, y)),
                                 __fmul_rn(z, z));
            stg[w * 256 + e] = make_float4(x, y, z, sn);
        }
        asm volatile("s_waitcnt lgkmcnt(0)" ::: "memory");
        int mbase = w * 1024 + h * 512 + sc * 128;
        const float4* mystg = stg + w * 256 + h * 128;
        #pragma unroll 1
        for (int cc = 0; cc < 128; cc += 8) {
            #pragma unroll
            for (int u = 0; u < 8; ++u) {
                float4 cp = mystg[cc + u];            // 2-addr broadcast read
                int m = mbase + cc + u;
                float dot = __fadd_rn(__fadd_rn(__fmul_rn(qx, cp.x),
                                                __fmul_rn(qy, cp.y)),
                                      __fmul_rn(qz, cp.z));
                float sq = __fadd_rn(__fsub_rn(snq, __fadd_rn(dot, dot)), cp.w);
                u32 bits = __float_as_uint(sq);
                u32 kb = bits ^ (0x80000000u | (u32)(((int)bits) >> 31));
                Cc[u] = ((u64)kb << 32) | (u32)m;
            }
            // Batcher sort-8 DESCENDING on Cc (19 CE)
            #define CS(i, j) { u64 _a = Cc[i], _b = Cc[j]; bool _t = _a > _b; \
                               Cc[i] = _t ? _a : _b; Cc[j] = _t ? _b : _a; }
            CS(0,1) CS(2,3) CS(4,5) CS(6,7)
            CS(0,2) CS(1,3) CS(4,6) CS(5,7)
            CS(1,2) CS(5,6)
            CS(0,4) CS(1,5) CS(2,6) CS(3,7)
            CS(2,4) CS(3,5)
            CS(1,2) CS(3,4) CS(5,6)
            #undef CS
            // pruned bitonic merge-32: (L[0..20] asc | +inf x3 | Cc desc)
            // outputs 0..20 ascending, in place.
            #define CE(i, j) { u64 _a = V(i), _b = V(j); bool _t = _a < _b; \
                               V(i) = _t ? _a : _b; V(j) = _t ? _b : _a; }
            // d=16: (5..7 vs phantoms pruned)
            CE(0,16) CE(1,17) CE(2,18) CE(3,19) CE(4,20)
            CE(8,24) CE(9,25) CE(10,26) CE(11,27) CE(12,28)
            CE(13,29) CE(14,30) CE(15,31)
            // d=8: lower full; upper (21..23 receive across phantom: movs)
            CE(0,8) CE(1,9) CE(2,10) CE(3,11) CE(4,12) CE(5,13) CE(6,14) CE(7,15)
            CE(16,24) CE(17,25) CE(18,26) CE(19,27) CE(20,28)
            V(21) = V(29); V(22) = V(30); V(23) = V(31);  // min(+inf,x)=x
            // d=4 (block 24-31 pruned)
            CE(0,4) CE(1,5) CE(2,6) CE(3,7)
            CE(8,12) CE(9,13) CE(10,14) CE(11,15)
            CE(16,20) CE(17,21) CE(18,22) CE(19,23)
            // d=2
            CE(0,2) CE(1,3) CE(4,6) CE(5,7) CE(8,10) CE(9,11)
            CE(12,14) CE(13,15) CE(16,18) CE(17,19) CE(20,22) CE(21,23)
            // d=1 (outputs 0..20)
            CE(0,1) CE(2,3) CE(4,5) CE(6,7) CE(8,9) CE(10,11)
            CE(12,13) CE(14,15) CE(16,17) CE(18,19) CE(20,21)
            #undef CE
        }
    }
    #undef V

    __syncthreads();                                  // phase-A staging dead
    #pragma unroll
    for (int j = 0; j < KNN; ++j) {
        mk[(w * 64 + l) * KNN + j] = (u32)(L[j] >> 32);
        mi[(w * 64 + l) * KNN + j] = (u16)(L[j] & 0xFFFFu);
    }
    __syncthreads();

    if (w == 0 && l < 32) {                           // 8-way merge, query = l
        int p0 = 0, p1 = 0, p2 = 0, p3 = 0, p4 = 0, p5 = 0, p6 = 0, p7 = 0;
        #pragma unroll 1
        for (int j = 0; j < KNN; ++j) {
            // list r = wave (r>>1), half (r&1) -> row (r>>1)*64 + l*2 + (r&1)
            #define LOADC(r, pr) \
                u64 c##r = ((u64)mk[(((r) >> 1) * 64 + l * 2 + ((r) & 1)) * KNN + pr] << 16) \
                         |  (u64)mi[(((r) >> 1) * 64 + l * 2 + ((r) & 1)) * KNN + pr];
            LOADC(0, p0) LOADC(1, p1) LOADC(2, p2) LOADC(3, p3)
            LOADC(4, p4) LOADC(5, p5) LOADC(6, p6) LOADC(7, p7)
            #undef LOADC
            u64 m01 = c0 < c1 ? c0 : c1; int s01 = c0 < c1 ? 0 : 1;
            u64 m23 = c2 < c3 ? c2 : c3; int s23 = c2 < c3 ? 2 : 3;
            u64 m45 = c4 < c5 ? c4 : c5; int s45 = c4 < c5 ? 4 : 5;
            u64 m67 = c6 < c7 ? c6 : c7; int s67 = c6 < c7 ? 6 : 7;
            u64 m03 = m01 < m23 ? m01 : m23; int s03 = m01 < m23 ? s01 : s23;
            u64 m47 = m45 < m67 ? m45 : m67; int s47 = m45 < m67 ? s45 : s67;
            u64 mm  = m03 < m47 ? m03 : m47; int sel = m03 < m47 ? s03 : s47;
            win[l * KNN + j] = (u16)(mm & 0xFFFFu);
            p0 += (sel == 0); p1 += (sel == 1); p2 += (sel == 2); p3 += (sel == 3);
            p4 += (sel == 4); p5 += (sel == 5); p6 += (sel == 6); p7 += (sel == 7);
        }
    }
    __syncthreads();

    // gather-sum: wave w handles 8 queries; lane covers channels 2l, 2l+1
    const u16* Xb = X + (size_t)b * N * C2;
    for (int qq = 0; qq < 8; ++qq) {
        int qg = w * 8 + qq;
        float f0 = 0.f, f1 = 0.f;
        #pragma unroll
        for (int j = 1; j < KNN; ++j) {               // skip nearest (j=0)
            int m = win[qg * KNN + j];
            u32 u2 = *(const u32*)(Xb + (size_t)m * C2 + 2 * l);
            f0 += bf2f((u16)(u2 & 0xFFFFu));
            f1 += bf2f((u16)(u2 >> 16));
        }
        u16* dst = X + ((size_t)b * N + n0 + qg) * C2 + 128 + 2 * l;
        *(u32*)dst = ((u32)f2bf(f1) << 16) | (u32)f2bf(f0);
    }
}

// ---------------------------------------------------------------------------
// K3: MFMA GEMM. out[b][o][n] = (W[o][:].X[b][n][:] + bc[o]+20bg[o])/21 + pts.
// Wave tile: 16(o) x 64(n), K=256 = 8 x mfma_f32_16x16x32_bf16 x 4 subtiles.
// A-frag loaded directly from Wc (kk<4) / Wg (kk>=4) fp32 rows, cvt f2bf.
// C/D map: col=lane&15 (n), row=(lane>>4)*4+reg (o)  [m89-verified]
// ---------------------------------------------------------------------------
__global__ __launch_bounds__(256) void k_gemm_mfma(
        const u16* __restrict__ X, const float* __restrict__ Wc,
        const float* __restrict__ Wg, const float* __restrict__ pts,
        const float* __restrict__ bc, const float* __restrict__ bg,
        float* __restrict__ out) {
    int wid = blockIdx.x * 4 + (threadIdx.x >> 6);   // 0..4095
    int lane = threadIdx.x & 63;
    int ot = wid & 7;            // 8 o-tiles of 16
    int nt = wid >> 3;           // 512 n-tiles of 64
    int b  = nt >> 6;            // 64 n-tiles per batch
    int n0 = (nt & 63) * 64;

    int l16 = lane & 15, lq = lane >> 4;
    const u16* Xb = X + (size_t)b * N * C2;
    const u16* bptr0 = Xb + (size_t)(n0 + 0 * 16 + l16) * C2 + lq * 8;
    const u16* bptr1 = Xb + (size_t)(n0 + 1 * 16 + l16) * C2 + lq * 8;
    const u16* bptr2 = Xb + (size_t)(n0 + 2 * 16 + l16) * C2 + lq * 8;
    const u16* bptr3 = Xb + (size_t)(n0 + 3 * 16 + l16) * C2 + lq * 8;
    const float* wrowc = Wc + (size_t)(ot * 16 + l16) * 128 + lq * 8;
    const float* wrowg = Wg + (size_t)(ot * 16 + l16) * 128 + lq * 8;

    f32x4 acc0 = {0.f, 0.f, 0.f, 0.f};
    f32x4 acc1 = {0.f, 0.f, 0.f, 0.f};
    f32x4 acc2 = {0.f, 0.f, 0.f, 0.f};
    f32x4 acc3 = {0.f, 0.f, 0.f, 0.f};
    #pragma unroll
    for (int kk = 0; kk < 8; ++kk) {
        const float* ws = (kk < 4) ? (wrowc + kk * 32) : (wrowg + (kk - 4) * 32);
        float4 wa = *(const float4*)ws;
        float4 wb = *(const float4*)(ws + 4);
        bf16x8 a;
        a[0] = (short)f2bf(wa.x); a[1] = (short)f2bf(wa.y);
        a[2] = (short)f2bf(wa.z); a[3] = (short)f2bf(wa.w);
        a[4] = (short)f2bf(wb.x); a[5] = (short)f2bf(wb.y);
        a[6] = (short)f2bf(wb.z); a[7] = (short)f2bf(wb.w);
        bf16x8 b0 = *(const bf16x8*)(bptr0 + kk * 32);
        bf16x8 b1 = *(const bf16x8*)(bptr1 + kk * 32);
        bf16x8 b2 = *(const bf16x8*)(bptr2 + kk * 32);
        bf16x8 b3 = *(const bf16x8*)(bptr3 + kk * 32);
        acc0 = __builtin_amdgcn_mfma_f32_16x16x32_bf16(a, b0, acc0, 0, 0, 0);
        acc1 = __builtin_amdgcn_mfma_f32_16x16x32_bf16(a, b1, acc1, 0, 0, 0);
        acc2 = __builtin_amdgcn_mfma_f32_16x16x32_bf16(a, b2, acc2, 0, 0, 0);
        acc3 = __builtin_amdgcn_mfma_f32_16x16x32_bf16(a, b3, acc3, 0, 0, 0);
    }

    const float inv21 = 1.0f / 21.0f;
    float bias[4];
    #pragma unroll
    for (int r = 0; r < 4; ++r) {
        int o = ot * 16 + lq * 4 + r;
        bias[r] = bc[o] + 20.f * bg[o];
    }
    const float* pb = pts + (size_t)b * C * N;
    float* ob = out + (size_t)b * C * N;
    f32x4 accs[4] = {acc0, acc1, acc2, acc3};
    #pragma unroll
    for (int t = 0; t < 4; ++t) {
        int n = n0 + t * 16 + l16;
        #pragma unroll
        for (int r = 0; r < 4; ++r) {
            int o = ot * 16 + lq * 4 + r;
            ob[(size_t)o * N + n] =
                (accs[t][r] + bias[r]) * inv21 + pb[(size_t)o * N + n];
        }
    }
}

// ---------------------------------------------------------------------------
extern "C" void kernel_launch(void* const* d_in, const int* in_sizes, int n_in,
                              void* d_out, int out_size, void* d_ws, size_t ws_size,
                              hipStream_t stream) {
    const float* xyz = (const float*)d_in[0];
    const float* pts = (const float*)d_in[1];
    const float* Wc  = (const float*)d_in[2];
    const float* bc  = (const float*)d_in[3];
    const float* Wg  = (const float*)d_in[4];
    const float* bg  = (const float*)d_in[5];
    float* out = (float*)d_out;

    u16* X = (u16*)d_ws;                              // B*N*C2 bf16 = 16 MB

    k_transpose_lrelu<<<dim3(N / 32, C / 32, B), dim3(32, 8), 0, stream>>>(pts, X);
    k_knn_gather<<<dim3(N / 32, B), dim3(256), 0, stream>>>(xyz, X);
    k_gemm_mfma<<<dim3(1024), dim3(256), 0, stream>>>(X, Wc, Wg, pts, bc, bg, out);
}

// Round 10
// 328.983 us; speedup vs baseline: 1.0729x; 1.0729x over previous
//
#include <hip/hip_runtime.h>

// Problem constants
#define B 8
#define N 4096
#define C 128
#define C2 256          // K-dim of fused GEMM: [ptl | s]
#define KNN 21          // top-(K+1), drop nearest
#define SCAP 24         // survivors capacity per lane (>=21; slack for key ties)

typedef unsigned long long u64;
typedef unsigned int u32;
typedef unsigned short u16;

typedef __attribute__((ext_vector_type(8))) short bf16x8;
typedef __attribute__((ext_vector_type(4))) float f32x4;

__device__ __forceinline__ float bf2f(u16 u) {
    return __uint_as_float(((u32)u) << 16);
}
__device__ __forceinline__ u16 f2bf(float f) {  // round-to-nearest-even
    u32 x = __float_as_uint(f);
    return (u16)((x + 0x7FFFu + ((x >> 16) & 1u)) >> 16);
}

// ---------------------------------------------------------------------------
// K1: transpose + leaky_relu: points (B,C,N) f32 -> X[b][n][c] (c<128) bf16
// ---------------------------------------------------------------------------
__global__ __launch_bounds__(256) void k_transpose_lrelu(
        const float* __restrict__ pts, u16* __restrict__ X) {
    __shared__ u16 tile[32][33];
    int b  = blockIdx.z;
    int c0 = blockIdx.y * 32;
    int n0 = blockIdx.x * 32;
    int tx = threadIdx.x, ty = threadIdx.y;   // 32 x 8
    const float* src = pts + (size_t)b * C * N;
    #pragma unroll
    for (int i = 0; i < 32; i += 8) {
        float v = src[(size_t)(c0 + ty + i) * N + n0 + tx];
        if (v < 0.f) v = __fmul_rn(v, 0.01f);
        tile[ty + i][tx] = f2bf(v);
    }
    __syncthreads();
    u16* dst = X + (size_t)b * N * C2;
    #pragma unroll
    for (int i = 0; i < 32; i += 8) {
        dst[(size_t)(n0 + ty + i) * C2 + (c0 + tx)] = tile[tx][ty + i];
    }
}

// ---------------------------------------------------------------------------
// K2: exact KNN (top-21 by (sq, idx), drop min) + neighbor-feature gather-sum.
// Grid 1024 blocks. Block = 32 queries, 256 thr = 4 waves.
// Lane l -> (query l>>1, half l&1); lane owns 512 candidates.
// PASS 1 (keys only): exact 21st-smallest key T via data-oblivious chunk-8
//   networks (u32 min/max CE).
// PASS 2 (survivors): append ALL kb<=T to per-lane LDS row (cap 24, sentinel
//   prefill). Survivors provably contain the top-21; no count arithmetic,
//   no overflow path.
// FINALIZE: per-lane bubble-network sort-24 on (key<<16|idx) u64 -> first 21
//   in lex (key,idx) order == np top_k tie-break.
// Then 8-way merge + gather-sum (unchanged, validated R5-R8).
// ---------------------------------------------------------------------------
__global__ __launch_bounds__(256) void k_knn_gather(
        const float* __restrict__ xyz, u16* __restrict__ X) {
    __shared__ __align__(16) char lds[45056];
    float4* stg = (float4*)lds;                       // [4][128]   8192 B
    u32*    ksv = (u32*)(lds + 8192);                 // [256][24] 24576 B
    u16*    isv = (u16*)(lds + 8192 + 24576);         // [256][24] 12288 B
    u16*    win = (u16*)lds;                          // [32][21] overlays stg

    int tid = threadIdx.x;
    int w = tid >> 6, l = tid & 63;
    int q = l >> 1, h = l & 1;
    int b = blockIdx.y;
    int n0 = blockIdx.x * 32;
    int nq = n0 + q;

    const float* xz = xyz + (size_t)b * 3 * N;
    // query point (np formula: ((x*x + y*y) + z*z))
    float qx = xz[nq], qy = xz[N + nq], qz = xz[2 * N + nq];
    float snq = __fadd_rn(__fadd_rn(__fmul_rn(qx, qx), __fmul_rn(qy, qy)),
                          __fmul_rn(qz, qz));

    u32 L[KNN];                                       // pos 0..20 asc (keys)
    u32 E[3];                                         // pos 21..23 (phantoms)
    u32 Cc[8];                                        // pos 24..31 (chunk desc)
    #pragma unroll
    for (int i = 0; i < KNN; ++i) L[i] = 0xFFFFFFFFu;

    #define V(p) ((p) <= 20 ? L[p] : ((p) <= 23 ? E[(p) - 21] : Cc[(p) - 24]))
    const float4* mystg = stg + w * 128 + h * 64;

    // ---------------- PASS 1: keys only ----------------
    for (int sc = 0; sc < 8; ++sc) {
        #pragma unroll
        for (int r = 0; r < 2; ++r) {
            int e = l + 64 * r;                       // 0..127
            int he = e >> 6, je = e & 63;
            int m = w * 1024 + he * 512 + sc * 64 + je;
            float x = xz[m], y = xz[N + m], z = xz[2 * N + m];
            float sn = __fadd_rn(__fadd_rn(__fmul_rn(x, x), __fmul_rn(y, y)),
                                 __fmul_rn(z, z));
            stg[w * 128 + e] = make_float4(x, y, z, sn);
        }
        asm volatile("s_waitcnt lgkmcnt(0)" ::: "memory");
        #pragma unroll 1
        for (int cc = 0; cc < 64; cc += 8) {
            #pragma unroll
            for (int u = 0; u < 8; ++u) {
                float4 cp = mystg[cc + u];            // 2-addr broadcast read
                float dot = __fadd_rn(__fadd_rn(__fmul_rn(qx, cp.x),
                                                __fmul_rn(qy, cp.y)),
                                      __fmul_rn(qz, cp.z));
                float sq = __fadd_rn(__fsub_rn(snq, __fadd_rn(dot, dot)), cp.w);
                u32 bits = __float_as_uint(sq);
                Cc[u] = bits ^ (0x80000000u | (u32)(((int)bits) >> 31));
            }
            // Batcher sort-8 DESCENDING on Cc (19 CE, min/max form)
            #define CS(i, j) { u32 _a = Cc[i], _b = Cc[j]; \
                               Cc[i] = _a > _b ? _a : _b; Cc[j] = _a > _b ? _b : _a; }
            CS(0,1) CS(2,3) CS(4,5) CS(6,7)
            CS(0,2) CS(1,3) CS(4,6) CS(5,7)
            CS(1,2) CS(5,6)
            CS(0,4) CS(1,5) CS(2,6) CS(3,7)
            CS(2,4) CS(3,5)
            CS(1,2) CS(3,4) CS(5,6)
            #undef CS
            // pruned bitonic merge-32 (L asc | 3 phantom | Cc desc), in place
            #define CE(i, j) { u32 _a = V(i), _b = V(j); \
                               V(i) = _a < _b ? _a : _b; V(j) = _a < _b ? _b : _a; }
            CE(0,16) CE(1,17) CE(2,18) CE(3,19) CE(4,20)
            CE(8,24) CE(9,25) CE(10,26) CE(11,27) CE(12,28)
            CE(13,29) CE(14,30) CE(15,31)
            CE(0,8) CE(1,9) CE(2,10) CE(3,11) CE(4,12) CE(5,13) CE(6,14) CE(7,15)
            CE(16,24) CE(17,25) CE(18,26) CE(19,27) CE(20,28)
            V(21) = V(29); V(22) = V(30); V(23) = V(31);  // min(+inf,x)=x
            CE(0,4) CE(1,5) CE(2,6) CE(3,7)
            CE(8,12) CE(9,13) CE(10,14) CE(11,15)
            CE(16,20) CE(17,21) CE(18,22) CE(19,23)
            CE(0,2) CE(1,3) CE(4,6) CE(5,7) CE(8,10) CE(9,11)
            CE(12,14) CE(13,15) CE(16,18) CE(17,19) CE(20,22) CE(21,23)
            CE(0,1) CE(2,3) CE(4,5) CE(6,7) CE(8,9) CE(10,11)
            CE(12,13) CE(14,15) CE(16,17) CE(18,19) CE(20,21)
            #undef CE
        }
    }
    #undef V

    // ---------------- PASS 2: survivors (kb <= T) ----------------
    u32 T = L[20];
    int row = tid;
    #pragma unroll
    for (int i = 0; i < SCAP; ++i) {                  // sentinel prefill
        ksv[row * SCAP + i] = 0xFFFFFFFFu;
        isv[row * SCAP + i] = 0;
    }
    int cnt = 0;
    for (int sc = 0; sc < 8; ++sc) {
        #pragma unroll
        for (int r = 0; r < 2; ++r) {
            int e = l + 64 * r;
            int he = e >> 6, je = e & 63;
            int m = w * 1024 + he * 512 + sc * 64 + je;
            float x = xz[m], y = xz[N + m], z = xz[2 * N + m];
            float sn = __fadd_rn(__fadd_rn(__fmul_rn(x, x), __fmul_rn(y, y)),
                                 __fmul_rn(z, z));
            stg[w * 128 + e] = make_float4(x, y, z, sn);
        }
        asm volatile("s_waitcnt lgkmcnt(0)" ::: "memory");
        int mb = w * 1024 + h * 512 + sc * 64;
        #pragma unroll 1
        for (int cc = 0; cc < 64; ++cc) {
            float4 cp = mystg[cc];
            float dot = __fadd_rn(__fadd_rn(__fmul_rn(qx, cp.x),
                                            __fmul_rn(qy, cp.y)),
                                  __fmul_rn(qz, cp.z));
            float sq = __fadd_rn(__fsub_rn(snq, __fadd_rn(dot, dot)), cp.w);
            u32 bits = __float_as_uint(sq);
            u32 kb = bits ^ (0x80000000u | (u32)(((int)bits) >> 31));
            if (kb <= T && cnt < SCAP) {
                ksv[row * SCAP + cnt] = kb;
                isv[row * SCAP + cnt] = (u16)(mb + cc);
                cnt++;
            }
        }
    }

    // ---------------- FINALIZE: per-lane sort-24, keep 21 ----------------
    {
        u64 z[SCAP];
        #pragma unroll
        for (int i = 0; i < SCAP; ++i)
            z[i] = ((u64)ksv[row * SCAP + i] << 16) | (u64)isv[row * SCAP + i];
        #pragma unroll
        for (int i = 0; i < SCAP; ++i) {
            #pragma unroll
            for (int j = 0; j < SCAP - 1 - i; ++j) {
                u64 _a = z[j], _b = z[j + 1];
                bool t = _a < _b;
                z[j] = t ? _a : _b; z[j + 1] = t ? _b : _a;
            }
        }
        #pragma unroll
        for (int j = 0; j < KNN; ++j) {
            ksv[row * SCAP + j] = (u32)(z[j] >> 16);
            isv[row * SCAP + j] = (u16)(z[j] & 0xFFFFu);
        }
    }
    __syncthreads();                                  // stg dead; rows final

    if (w == 0 && l < 32) {                           // 8-way merge, query = l
        int p0 = 0, p1 = 0, p2 = 0, p3 = 0, p4 = 0, p5 = 0, p6 = 0, p7 = 0;
        #pragma unroll 1
        for (int j = 0; j < KNN; ++j) {
            // list r = wave (r>>1), half (r&1) -> row (r>>1)*64 + l*2 + (r&1)
            #define LOADC(r, pr) \
                u64 c##r = ((u64)ksv[(((r) >> 1) * 64 + l * 2 + ((r) & 1)) * SCAP + pr] << 16) \
                         |  (u64)isv[(((r) >> 1) * 64 + l * 2 + ((r) & 1)) * SCAP + pr];
            LOADC(0, p0) LOADC(1, p1) LOADC(2, p2) LOADC(3, p3)
            LOADC(4, p4) LOADC(5, p5) LOADC(6, p6) LOADC(7, p7)
            #undef LOADC
            u64 m01 = c0 < c1 ? c0 : c1; int s01 = c0 < c1 ? 0 : 1;
            u64 m23 = c2 < c3 ? c2 : c3; int s23 = c2 < c3 ? 2 : 3;
            u64 m45 = c4 < c5 ? c4 : c5; int s45 = c4 < c5 ? 4 : 5;
            u64 m67 = c6 < c7 ? c6 : c7; int s67 = c6 < c7 ? 6 : 7;
            u64 m03 = m01 < m23 ? m01 : m23; int s03 = m01 < m23 ? s01 : s23;
            u64 m47 = m45 < m67 ? m45 : m67; int s47 = m45 < m67 ? s45 : s67;
            u64 mm  = m03 < m47 ? m03 : m47; int sel = m03 < m47 ? s03 : s47;
            win[l * KNN + j] = (u16)(mm & 0xFFFFu);
            p0 += (sel == 0); p1 += (sel == 1); p2 += (sel == 2); p3 += (sel == 3);
            p4 += (sel == 4); p5 += (sel == 5); p6 += (sel == 6); p7 += (sel == 7);
        }
    }
    __syncthreads();

    // gather-sum: wave w handles 8 queries; lane covers channels 2l, 2l+1
    const u16* Xb = X + (size_t)b * N * C2;
    for (int qq = 0; qq < 8; ++qq) {
        int qg = w * 8 + qq;
        float f0 = 0.f, f1 = 0.f;
        #pragma unroll
        for (int j = 1; j < KNN; ++j) {               // skip nearest (j=0)
            int m = win[qg * KNN + j];
            u32 u2 = *(const u32*)(Xb + (size_t)m * C2 + 2 * l);
            f0 += bf2f((u16)(u2 & 0xFFFFu));
            f1 += bf2f((u16)(u2 >> 16));
        }
        u16* dst = X + ((size_t)b * N + n0 + qg) * C2 + 128 + 2 * l;
        *(u32*)dst = ((u32)f2bf(f1) << 16) | (u32)f2bf(f0);
    }
}

// ---------------------------------------------------------------------------
// K3: MFMA GEMM. out[b][o][n] = (W[o][:].X[b][n][:] + bc[o]+20bg[o])/21 + pts.
// Wave tile: 16(o) x 64(n), K=256 = 8 x mfma_f32_16x16x32_bf16 x 4 subtiles.
// A-frag loaded directly from Wc (kk<4) / Wg (kk>=4) fp32 rows, cvt f2bf.
// C/D map: col=lane&15 (n), row=(lane>>4)*4+reg (o)  [m89-verified]
// ---------------------------------------------------------------------------
__global__ __launch_bounds__(256) void k_gemm_mfma(
        const u16* __restrict__ X, const float* __restrict__ Wc,
        const float* __restrict__ Wg, const float* __restrict__ pts,
        const float* __restrict__ bc, const float* __restrict__ bg,
        float* __restrict__ out) {
    int wid = blockIdx.x * 4 + (threadIdx.x >> 6);   // 0..4095
    int lane = threadIdx.x & 63;
    int ot = wid & 7;            // 8 o-tiles of 16
    int nt = wid >> 3;           // 512 n-tiles of 64
    int b  = nt >> 6;            // 64 n-tiles per batch
    int n0 = (nt & 63) * 64;

    int l16 = lane & 15, lq = lane >> 4;
    const u16* Xb = X + (size_t)b * N * C2;
    const u16* bptr0 = Xb + (size_t)(n0 + 0 * 16 + l16) * C2 + lq * 8;
    const u16* bptr1 = Xb + (size_t)(n0 + 1 * 16 + l16) * C2 + lq * 8;
    const u16* bptr2 = Xb + (size_t)(n0 + 2 * 16 + l16) * C2 + lq * 8;
    const u16* bptr3 = Xb + (size_t)(n0 + 3 * 16 + l16) * C2 + lq * 8;
    const float* wrowc = Wc + (size_t)(ot * 16 + l16) * 128 + lq * 8;
    const float* wrowg = Wg + (size_t)(ot * 16 + l16) * 128 + lq * 8;

    f32x4 acc0 = {0.f, 0.f, 0.f, 0.f};
    f32x4 acc1 = {0.f, 0.f, 0.f, 0.f};
    f32x4 acc2 = {0.f, 0.f, 0.f, 0.f};
    f32x4 acc3 = {0.f, 0.f, 0.f, 0.f};
    #pragma unroll
    for (int kk = 0; kk < 8; ++kk) {
        const float* ws = (kk < 4) ? (wrowc + kk * 32) : (wrowg + (kk - 4) * 32);
        float4 wa = *(const float4*)ws;
        float4 wb = *(const float4*)(ws + 4);
        bf16x8 a;
        a[0] = (short)f2bf(wa.x); a[1] = (short)f2bf(wa.y);
        a[2] = (short)f2bf(wa.z); a[3] = (short)f2bf(wa.w);
        a[4] = (short)f2bf(wb.x); a[5] = (short)f2bf(wb.y);
        a[6] = (short)f2bf(wb.z); a[7] = (short)f2bf(wb.w);
        bf16x8 b0 = *(const bf16x8*)(bptr0 + kk * 32);
        bf16x8 b1 = *(const bf16x8*)(bptr1 + kk * 32);
        bf16x8 b2 = *(const bf16x8*)(bptr2 + kk * 32);
        bf16x8 b3 = *(const bf16x8*)(bptr3 + kk * 32);
        acc0 = __builtin_amdgcn_mfma_f32_16x16x32_bf16(a, b0, acc0, 0, 0, 0);
        acc1 = __builtin_amdgcn_mfma_f32_16x16x32_bf16(a, b1, acc1, 0, 0, 0);
        acc2 = __builtin_amdgcn_mfma_f32_16x16x32_bf16(a, b2, acc2, 0, 0, 0);
        acc3 = __builtin_amdgcn_mfma_f32_16x16x32_bf16(a, b3, acc3, 0, 0, 0);
    }

    const float inv21 = 1.0f / 21.0f;
    float bias[4];
    #pragma unroll
    for (int r = 0; r < 4; ++r) {
        int o = ot * 16 + lq * 4 + r;
        bias[r] = bc[o] + 20.f * bg[o];
    }
    const float* pb = pts + (size_t)b * C * N;
    float* ob = out + (size_t)b * C * N;
    f32x4 accs[4] = {acc0, acc1, acc2, acc3};
    #pragma unroll
    for (int t = 0; t < 4; ++t) {
        int n = n0 + t * 16 + l16;
        #pragma unroll
        for (int r = 0; r < 4; ++r) {
            int o = ot * 16 + lq * 4 + r;
            ob[(size_t)o * N + n] =
                (accs[t][r] + bias[r]) * inv21 + pb[(size_t)o * N + n];
        }
    }
}

// ---------------------------------------------------------------------------
extern "C" void kernel_launch(void* const* d_in, const int* in_sizes, int n_in,
                              void* d_out, int out_size, void* d_ws, size_t ws_size,
                              hipStream_t stream) {
    const float* xyz = (const float*)d_in[0];
    const float* pts = (const float*)d_in[1];
    const float* Wc  = (const float*)d_in[2];
    const float* bc  = (const float*)d_in[3];
    const float* Wg  = (const float*)d_in[4];
    const float* bg  = (const float*)d_in[5];
    float* out = (float*)d_out;

    u16* X = (u16*)d_ws;                              // B*N*C2 bf16 = 16 MB

    k_transpose_lrelu<<<dim3(N / 32, C / 32, B), dim3(32, 8), 0, stream>>>(pts, X);
    k_knn_gather<<<dim3(N / 32, B), dim3(256), 0, stream>>>(xyz, X);
    k_gemm_mfma<<<dim3(1024), dim3(256), 0, stream>>>(X, Wc, Wg, pts, bc, bg, out);
}